// Round 3
// baseline (339.458 us; speedup 1.0000x reference)
//
#include <hip/hip_runtime.h>

#define NN 200000      // nodes; D=128 features, 40 classes (padded to 48 in wt)
#define NW 16          // waves per block (W3 evicted from LDS to fit 16 waves)
#define NBLK 256       // persistent blocks (1 per CU; LDS pins 1 block/CU)
#define NT 12500       // tiles of 16 rows: 12500*16 = NN exactly
#define WSTRIDE (NBLK * NW)   // 4096 global waves

typedef __attribute__((ext_vector_type(8))) short bf16x8;
typedef __attribute__((ext_vector_type(4))) float f32x4;
typedef __attribute__((ext_vector_type(4))) unsigned int u32x4;

// round-to-nearest-even fp32 -> bf16 bits (prep kernel only)
static __device__ __forceinline__ short f2bf(float f) {
    unsigned u = __builtin_bit_cast(unsigned, f);
    u += 0x7fffu + ((u >> 16) & 1u);
    return (short)(u >> 16);
}

// pack 2 floats -> 2 bf16 in one u32 (round-half-up)
static __device__ __forceinline__ unsigned pk2(float a, float b) {
    unsigned ua = __builtin_bit_cast(unsigned, a) + 0x8000u;
    unsigned ub = __builtin_bit_cast(unsigned, b) + 0x8000u;
    return __builtin_amdgcn_perm(ub, ua, 0x07060302u);
}

// XOR-swizzled LDS offset for element (r, k) of a [*,128] bf16 table.
// 16B chunks xored with (r&15) -> conflict-free ds_read_b128 fragments.
static __device__ __forceinline__ int swz(int r, int k) {
    return (r << 7) + (((k >> 3) ^ (r & 15)) << 3) + (k & 7);
}

// Pre-transpose + bf16-convert weights into workspace (elements):
// [0) Wt0[n][k]=W0[k][n] 128x128 | [16384) Wt1 | [32768) Wt2 | [49152) Wt3 48x128 (n>=40 zero)
__global__ void prep_weights_k(const float* __restrict__ W0, const float* __restrict__ W1,
                               const float* __restrict__ W2, const float* __restrict__ W3,
                               short* __restrict__ wt) {
    int e = blockIdx.x * 256 + threadIdx.x;   // 216 blocks * 256 = 55296
    if (e < 49152) {
        int l = e >> 14;
        int i = e & 16383;
        int n = i >> 7, k = i & 127;
        const float* W = (l == 0) ? W0 : ((l == 1) ? W1 : W2);
        wt[e] = f2bf(W[(k << 7) + n]);
    } else if (e < 55296) {
        int i = e - 49152;
        int n = i >> 7, k = i & 127;
        wt[e] = (n < 40) ? f2bf(W3[k * 40 + n]) : (short)0;
    }
}

// Persistent fused 4-layer MLP + log_softmax.
//  - layers 0-2 weights (96KB bf16, swizzled) staged into LDS ONCE per block,
//    then ONE barrier; afterwards waves are fully independent.
//  - layer-3 B-fragments (12KB table) read directly from global each tile:
//    L1/L2-resident, 12 x b128 per tile, frees 12KB LDS -> 16 waves/block.
//  - each wave grid-strides over 16-row tiles; x prefetched one tile deep,
//    raw f32 packed to bf16 MID-BODY (loads long done; raw regs die there).
//  - activations round-trip a per-wave-private 4KB LDS slice.
// LDS total = 98304 + 65536 = 163840 B == gfx950 max -> 1 block/CU, 16 waves (4/SIMD).
// __launch_bounds__(1024, 4): 2nd arg = min waves per EU. Pins the allocator
// to the LDS-imposed occupancy -> full 128-VGPR budget, NO spill (round-1
// regression was launch_bounds-alone squeezing to 64 VGPRs and spilling
// ~135MB each way to scratch).
__global__ __launch_bounds__(1024, 4)
void mlp_fused_k(const float* __restrict__ x, const short* __restrict__ wt,
                 const float* __restrict__ b0, const float* __restrict__ b1,
                 const float* __restrict__ b2, const float* __restrict__ b3,
                 float* __restrict__ out) {
    __shared__ __align__(16) short sW[49152];       // layers 0-2, swizzled
    __shared__ __align__(16) short sA[NW][2048];    // per-wave activation slices

    const int tid  = (int)threadIdx.x;
    const int lane = tid & 63;
    const int wv   = tid >> 6;       // wave 0..15
    const int m    = lane & 15;      // row (A) / col (B,C) within 16-tile
    const int quad = lane >> 4;      // 0..3
    short* sAw = &sA[wv][0];

    // ---- stage layers 0-2 global->LDS (swizzled), 6144 16B chunks = 6*1024 ----
    {
        const u32x4* src = (const u32x4*)wt;
        #pragma unroll
        for (int i = 0; i < 6; ++i) {
            int q = tid + i * 1024;            // exactly 6144 total, no tail
            int R = q >> 4, c = q & 15;
            *(u32x4*)&sW[(R << 7) + ((c ^ (R & 15)) << 3)] = src[q];
        }
    }
    __syncthreads();   // the ONLY barrier

    // ---- hoist biases (tile-invariant, per-lane) ----
    float bv0[8], bv1[8], bv2[8];
    #pragma unroll
    for (int ct = 0; ct < 8; ++ct) {
        bv0[ct] = b0[(ct << 4) + m];
        bv1[ct] = b1[(ct << 4) + m];
        bv2[ct] = b2[(ct << 4) + m];
    }
    const bool val2 = (m < 8);
    float b3v0 = b3[m], b3v1 = b3[16 + m], b3v2 = val2 ? b3[32 + m] : 0.f;

    f32x4 acc[8];
    auto zacc = [&]() {
        #pragma unroll
        for (int ct = 0; ct < 8; ++ct)
            #pragma unroll
            for (int r = 0; r < 4; ++r) acc[ct][r] = 0.f;
    };

    // bias + SiLU + bf16 -> sAw (wave-private 16 rows)
    auto epilogue = [&](const float* bv) {
        #pragma unroll
        for (int ct = 0; ct < 8; ++ct)
            #pragma unroll
            for (int r = 0; r < 4; ++r) {
                float v = acc[ct][r] + bv[ct];
                float h = v * __builtin_amdgcn_rcpf(1.f + __expf(-v));
                int rl = (quad << 2) + r;                // C/D: row = quad*4+reg
                unsigned u = __builtin_bit_cast(unsigned, h) + 0x8000u;
                sAw[swz(rl, (ct << 4) + m)] = (short)(u >> 16);
            }
    };

    // dense layer: A from wave-private slice, B from resident sW
    auto dense = [&](int lbase) {
        zacc();
        #pragma unroll
        for (int ks = 0; ks < 4; ++ks) {
            int kk = (ks << 5) + (quad << 3);
            bf16x8 a0 = *(const bf16x8*)&sAw[swz(m, kk)];
            #pragma unroll
            for (int ct = 0; ct < 8; ++ct) {
                bf16x8 b = *(const bf16x8*)&sW[lbase + swz((ct << 4) + m, kk)];
                acc[ct] = __builtin_amdgcn_mfma_f32_16x16x32_bf16(a0, b, acc[ct], 0, 0, 0);
            }
        }
    };

    // raw x load for tile tt (8 f32x4, issued early for latency cover)
    auto loadraw = [&](int tt, f32x4* raw) {
        const f32x4* p = (const f32x4*)(x + ((long)(tt * 16 + m) << 7)) + quad * 2;
        #pragma unroll
        for (int ks = 0; ks < 4; ++ks) { raw[ks * 2] = p[ks * 8]; raw[ks * 2 + 1] = p[ks * 8 + 1]; }
    };
    // pack 8 f32x4 -> 4 u32x4 of bf16 (A-fragments per ks)
    auto packx = [&](const f32x4* raw, u32x4* xp) {
        #pragma unroll
        for (int ks = 0; ks < 4; ++ks) {
            f32x4 va = raw[ks * 2], vb = raw[ks * 2 + 1];
            u32x4 ua;
            ua[0] = pk2(va[0], va[1]); ua[1] = pk2(va[2], va[3]);
            ua[2] = pk2(vb[0], vb[1]); ua[3] = pk2(vb[2], vb[3]);
            xp[ks] = ua;
        }
    };

    // ---- persistent tile loop with one-deep x prefetch ----
    int t = (int)blockIdx.x * NW + wv;       // first tile for this wave (< WSTRIDE <= NT)
    u32x4 xp[4];                             // packed A-operand for current tile
    {
        f32x4 raw[8];
        loadraw(t, raw);
        packx(raw, xp);                      // prologue stall acceptable
    }

    while (true) {
        int tn = t + WSTRIDE;
        bool has = tn < NT;                   // wave-uniform
        f32x4 xraw[8];
        if (has) loadraw(tn, xraw);           // issue loads at top: max latency cover

        // layer 0: A from packed regs
        zacc();
        #pragma unroll
        for (int ks = 0; ks < 4; ++ks) {
            bf16x8 a0 = __builtin_bit_cast(bf16x8, xp[ks]);
            int kk = (ks << 5) + (quad << 3);
            #pragma unroll
            for (int ct = 0; ct < 8; ++ct) {
                bf16x8 b = *(const bf16x8*)&sW[swz((ct << 4) + m, kk)];
                acc[ct] = __builtin_amdgcn_mfma_f32_16x16x32_bf16(a0, b, acc[ct], 0, 0, 0);
            }
        }
        epilogue(bv0);
        dense(16384);
        epilogue(bv1);

        // pack next tile mid-body: loads are ~1500cy old (vmcnt free); xraw dies here
        u32x4 xpn[4];
        if (has) packx(xraw, xpn);

        dense(32768);
        epilogue(bv2);

        // layer 3 (48 padded cols, B direct from global wt: 12KB L1/L2-resident)
        f32x4 c3[3];
        #pragma unroll
        for (int ct = 0; ct < 3; ++ct)
            #pragma unroll
            for (int r = 0; r < 4; ++r) c3[ct][r] = 0.f;
        #pragma unroll
        for (int ks = 0; ks < 4; ++ks) {
            int kk = (ks << 5) + (quad << 3);
            bf16x8 a0 = *(const bf16x8*)&sAw[swz(m, kk)];
            #pragma unroll
            for (int ct = 0; ct < 3; ++ct) {
                bf16x8 b = *(const bf16x8*)&wt[49152 + (((ct << 4) + m) << 7) + kk];
                c3[ct] = __builtin_amdgcn_mfma_f32_16x16x32_bf16(a0, b, c3[ct], 0, 0, 0);
            }
        }
        #pragma unroll
        for (int r = 0; r < 4; ++r) {
            float v0 = c3[0][r] + b3v0;
            float v1 = c3[1][r] + b3v1;
            float v2 = c3[2][r] + b3v2;
            float mx = fmaxf(v0, v1);
            mx = val2 ? fmaxf(mx, v2) : mx;
            #pragma unroll
            for (int s = 1; s < 16; s <<= 1)
                mx = fmaxf(mx, __shfl_xor(mx, s, 64));
            float sm = __expf(v0 - mx) + __expf(v1 - mx) + (val2 ? __expf(v2 - mx) : 0.f);
            #pragma unroll
            for (int s = 1; s < 16; s <<= 1)
                sm += __shfl_xor(sm, s, 64);
            float L = mx + __logf(sm);
            int grow = t * 16 + (quad << 2) + r;   // C/D: row = quad*4+reg
            float* orow = out + (long)grow * 40;
            orow[m]      = v0 - L;
            orow[16 + m] = v1 - L;
            if (val2) orow[32 + m] = v2 - L;
        }

        if (!has) break;
        #pragma unroll
        for (int i = 0; i < 4; ++i) xp[i] = xpn[i];
        t = tn;
    }
}

extern "C" void kernel_launch(void* const* d_in, const int* in_sizes, int n_in,
                              void* d_out, int out_size, void* d_ws, size_t ws_size,
                              hipStream_t stream) {
    const float* x   = (const float*)d_in[0];
    // d_in[1] = edge_index (unused: ChebConv K=1 ignores the Laplacian)
    const float* W0  = (const float*)d_in[2];
    const float* bb0 = (const float*)d_in[3];
    const float* W1  = (const float*)d_in[4];
    const float* bb1 = (const float*)d_in[5];
    const float* W2  = (const float*)d_in[6];
    const float* bb2 = (const float*)d_in[7];
    const float* W3  = (const float*)d_in[8];
    const float* bb3 = (const float*)d_in[9];
    short* wt  = (short*)d_ws;         // 110592 B of bf16 transposed weights
    float* out = (float*)d_out;

    hipLaunchKernelGGL(prep_weights_k, dim3(216), dim3(256), 0, stream, W0, W1, W2, W3, wt);
    hipLaunchKernelGGL(mlp_fused_k, dim3(NBLK), dim3(1024), 0, stream,
                       x, wt, bb0, bb1, bb2, bb3, out);
}

// Round 4
// 306.365 us; speedup vs baseline: 1.1080x; 1.1080x over previous
//
#include <hip/hip_runtime.h>

#define NN 200000      // nodes; D=128 features, 40 classes (padded to 48 in wt)
#define NW 16          // waves per block (W3 evicted from LDS to fit 16 waves)
#define NBLK 256       // persistent blocks (1 per CU; LDS pins 1 block/CU)
#define NT 12500       // tiles of 16 rows: 12500*16 = NN exactly
#define WSTRIDE (NBLK * NW)   // 4096 global waves

typedef __attribute__((ext_vector_type(8))) short bf16x8;
typedef __attribute__((ext_vector_type(4))) float f32x4;
typedef __attribute__((ext_vector_type(4))) unsigned int u32x4;

// round-to-nearest-even fp32 -> bf16 bits (prep kernel only)
static __device__ __forceinline__ short f2bf(float f) {
    unsigned u = __builtin_bit_cast(unsigned, f);
    u += 0x7fffu + ((u >> 16) & 1u);
    return (short)(u >> 16);
}

// pack 2 floats -> 2 bf16 in one u32 (round-half-up)
static __device__ __forceinline__ unsigned pk2(float a, float b) {
    unsigned ua = __builtin_bit_cast(unsigned, a) + 0x8000u;
    unsigned ub = __builtin_bit_cast(unsigned, b) + 0x8000u;
    return __builtin_amdgcn_perm(ub, ua, 0x07060302u);
}

// XOR-swizzled LDS offset for element (r, k) of a [*,128] bf16 table.
// 16B chunks xored with (r&15) -> conflict-free ds_read_b128 fragments.
static __device__ __forceinline__ int swz(int r, int k) {
    return (r << 7) + (((k >> 3) ^ (r & 15)) << 3) + (k & 7);
}

// Pre-transpose + bf16-convert weights into workspace (elements):
// [0) Wt0[n][k]=W0[k][n] 128x128 | [16384) Wt1 | [32768) Wt2 | [49152) Wt3 48x128 (n>=40 zero)
__global__ void prep_weights_k(const float* __restrict__ W0, const float* __restrict__ W1,
                               const float* __restrict__ W2, const float* __restrict__ W3,
                               short* __restrict__ wt) {
    int e = blockIdx.x * 256 + threadIdx.x;   // 216 blocks * 256 = 55296
    if (e < 49152) {
        int l = e >> 14;
        int i = e & 16383;
        int n = i >> 7, k = i & 127;
        const float* W = (l == 0) ? W0 : ((l == 1) ? W1 : W2);
        wt[e] = f2bf(W[(k << 7) + n]);
    } else if (e < 55296) {
        int i = e - 49152;
        int n = i >> 7, k = i & 127;
        wt[e] = (n < 40) ? f2bf(W3[k * 40 + n]) : (short)0;
    }
}

// Persistent fused 4-layer MLP + log_softmax.
//  - layers 0-2 weights (96KB bf16, swizzled) staged into LDS ONCE per block,
//    then ONE barrier; afterwards waves are fully independent.
//  - layer-3 B-fragments (12KB table) read directly from global each tile:
//    L1/L2-resident, frees 12KB LDS -> 16 waves/block (4 waves/EU).
//  - x prefetched one tile deep; loads ISSUED after epilogue(bv2) where
//    acc[8] is dead, so the 32 raw f32 regs reuse acc's slots (no live-range
//    overlap) and stay in flight across layer3+softmax (~1500cy cover).
//  - activations round-trip a per-wave-private 4KB LDS slice.
// LDS total = 98304 + 65536 = 163840 B == gfx950 max -> 1 block/CU, 16 waves (4/SIMD).
// amdgpu_waves_per_eu(4,4): pins the allocator's occupancy TARGET (min AND
// max) to the LDS-imposed 4 waves/EU -> full 128-VGPR budget. Rounds 1/3
// showed launch_bounds alone leaves the target at 8 waves/EU -> 64-VGPR
// squeeze -> ~180MB/side scratch spill.
__global__ __launch_bounds__(1024) __attribute__((amdgpu_waves_per_eu(4, 4)))
void mlp_fused_k(const float* __restrict__ x, const short* __restrict__ wt,
                 const float* __restrict__ b0, const float* __restrict__ b1,
                 const float* __restrict__ b2, const float* __restrict__ b3,
                 float* __restrict__ out) {
    __shared__ __align__(16) short sW[49152];       // layers 0-2, swizzled
    __shared__ __align__(16) short sA[NW][2048];    // per-wave activation slices

    const int tid  = (int)threadIdx.x;
    const int lane = tid & 63;
    const int wv   = tid >> 6;       // wave 0..15
    const int m    = lane & 15;      // row (A) / col (B,C) within 16-tile
    const int quad = lane >> 4;      // 0..3
    short* sAw = &sA[wv][0];

    // ---- stage layers 0-2 global->LDS (swizzled), 6144 16B chunks = 6*1024 ----
    {
        const u32x4* src = (const u32x4*)wt;
        #pragma unroll
        for (int i = 0; i < 6; ++i) {
            int q = tid + i * 1024;            // exactly 6144 total, no tail
            int R = q >> 4, c = q & 15;
            *(u32x4*)&sW[(R << 7) + ((c ^ (R & 15)) << 3)] = src[q];
        }
    }
    __syncthreads();   // the ONLY barrier

    // ---- hoist biases (tile-invariant, per-lane) ----
    float bv0[8], bv1[8], bv2[8];
    #pragma unroll
    for (int ct = 0; ct < 8; ++ct) {
        bv0[ct] = b0[(ct << 4) + m];
        bv1[ct] = b1[(ct << 4) + m];
        bv2[ct] = b2[(ct << 4) + m];
    }
    const bool val2 = (m < 8);
    float b3v0 = b3[m], b3v1 = b3[16 + m], b3v2 = val2 ? b3[32 + m] : 0.f;

    f32x4 acc[8];
    auto zacc = [&]() {
        #pragma unroll
        for (int ct = 0; ct < 8; ++ct)
            #pragma unroll
            for (int r = 0; r < 4; ++r) acc[ct][r] = 0.f;
    };

    // bias + SiLU + bf16 -> sAw (wave-private 16 rows)
    auto epilogue = [&](const float* bv) {
        #pragma unroll
        for (int ct = 0; ct < 8; ++ct)
            #pragma unroll
            for (int r = 0; r < 4; ++r) {
                float v = acc[ct][r] + bv[ct];
                float h = v * __builtin_amdgcn_rcpf(1.f + __expf(-v));
                int rl = (quad << 2) + r;                // C/D: row = quad*4+reg
                unsigned u = __builtin_bit_cast(unsigned, h) + 0x8000u;
                sAw[swz(rl, (ct << 4) + m)] = (short)(u >> 16);
            }
    };

    // dense layer: A from wave-private slice, B from resident sW
    auto dense = [&](int lbase) {
        zacc();
        #pragma unroll
        for (int ks = 0; ks < 4; ++ks) {
            int kk = (ks << 5) + (quad << 3);
            bf16x8 a0 = *(const bf16x8*)&sAw[swz(m, kk)];
            #pragma unroll
            for (int ct = 0; ct < 8; ++ct) {
                bf16x8 b = *(const bf16x8*)&sW[lbase + swz((ct << 4) + m, kk)];
                acc[ct] = __builtin_amdgcn_mfma_f32_16x16x32_bf16(a0, b, acc[ct], 0, 0, 0);
            }
        }
    };

    // raw x load for tile tt (8 f32x4)
    auto loadraw = [&](int tt, f32x4* raw) {
        const f32x4* p = (const f32x4*)(x + ((long)(tt * 16 + m) << 7)) + quad * 2;
        #pragma unroll
        for (int ks = 0; ks < 4; ++ks) { raw[ks * 2] = p[ks * 8]; raw[ks * 2 + 1] = p[ks * 8 + 1]; }
    };
    // pack 8 f32x4 -> 4 u32x4 of bf16 (A-fragments per ks)
    auto packx = [&](const f32x4* raw, u32x4* xp) {
        #pragma unroll
        for (int ks = 0; ks < 4; ++ks) {
            f32x4 va = raw[ks * 2], vb = raw[ks * 2 + 1];
            u32x4 ua;
            ua[0] = pk2(va[0], va[1]); ua[1] = pk2(va[2], va[3]);
            ua[2] = pk2(vb[0], vb[1]); ua[3] = pk2(vb[2], vb[3]);
            xp[ks] = ua;
        }
    };

    // ---- persistent tile loop; x loads one tile deep, issued where acc is dead ----
    int t = (int)blockIdx.x * NW + wv;       // first tile for this wave (< WSTRIDE <= NT)
    f32x4 raw[8];                            // in-flight x (loop-carried)
    loadraw(t, raw);

    while (true) {
        // pack x for CURRENT tile (loads issued last iteration / prologue)
        u32x4 xp[4];
        packx(raw, xp);

        // layer 0: A from packed regs
        zacc();
        #pragma unroll
        for (int ks = 0; ks < 4; ++ks) {
            bf16x8 a0 = __builtin_bit_cast(bf16x8, xp[ks]);
            int kk = (ks << 5) + (quad << 3);
            #pragma unroll
            for (int ct = 0; ct < 8; ++ct) {
                bf16x8 b = *(const bf16x8*)&sW[swz((ct << 4) + m, kk)];
                acc[ct] = __builtin_amdgcn_mfma_f32_16x16x32_bf16(a0, b, acc[ct], 0, 0, 0);
            }
        }
        epilogue(bv0);
        dense(16384);
        epilogue(bv1);
        dense(32768);
        epilogue(bv2);
        // acc dead from here to loop end -> raw[] reuses its register slots

        int tn = t + WSTRIDE;
        bool has = tn < NT;                   // wave-uniform
        if (has) loadraw(tn, raw);            // in flight across layer3+softmax+store

        // layer 3 (48 padded cols, B direct from global wt: 12KB L1/L2-resident)
        f32x4 c3[3];
        #pragma unroll
        for (int ct = 0; ct < 3; ++ct)
            #pragma unroll
            for (int r = 0; r < 4; ++r) c3[ct][r] = 0.f;
        #pragma unroll
        for (int ks = 0; ks < 4; ++ks) {
            int kk = (ks << 5) + (quad << 3);
            bf16x8 a0 = *(const bf16x8*)&sAw[swz(m, kk)];
            #pragma unroll
            for (int ct = 0; ct < 3; ++ct) {
                bf16x8 b = *(const bf16x8*)&wt[49152 + (((ct << 4) + m) << 7) + kk];
                c3[ct] = __builtin_amdgcn_mfma_f32_16x16x32_bf16(a0, b, c3[ct], 0, 0, 0);
            }
        }
        #pragma unroll
        for (int r = 0; r < 4; ++r) {
            float v0 = c3[0][r] + b3v0;
            float v1 = c3[1][r] + b3v1;
            float v2 = c3[2][r] + b3v2;
            float mx = fmaxf(v0, v1);
            mx = val2 ? fmaxf(mx, v2) : mx;
            #pragma unroll
            for (int s = 1; s < 16; s <<= 1)
                mx = fmaxf(mx, __shfl_xor(mx, s, 64));
            float sm = __expf(v0 - mx) + __expf(v1 - mx) + (val2 ? __expf(v2 - mx) : 0.f);
            #pragma unroll
            for (int s = 1; s < 16; s <<= 1)
                sm += __shfl_xor(sm, s, 64);
            float L = mx + __logf(sm);
            int grow = t * 16 + (quad << 2) + r;   // C/D: row = quad*4+reg
            float* orow = out + (long)grow * 40;
            orow[m]      = v0 - L;
            orow[16 + m] = v1 - L;
            if (val2) orow[32 + m] = v2 - L;
        }

        if (!has) break;
        t = tn;
    }
}

extern "C" void kernel_launch(void* const* d_in, const int* in_sizes, int n_in,
                              void* d_out, int out_size, void* d_ws, size_t ws_size,
                              hipStream_t stream) {
    const float* x   = (const float*)d_in[0];
    // d_in[1] = edge_index (unused: ChebConv K=1 ignores the Laplacian)
    const float* W0  = (const float*)d_in[2];
    const float* bb0 = (const float*)d_in[3];
    const float* W1  = (const float*)d_in[4];
    const float* bb1 = (const float*)d_in[5];
    const float* W2  = (const float*)d_in[6];
    const float* bb2 = (const float*)d_in[7];
    const float* W3  = (const float*)d_in[8];
    const float* bb3 = (const float*)d_in[9];
    short* wt  = (short*)d_ws;         // 110592 B of bf16 transposed weights
    float* out = (float*)d_out;

    hipLaunchKernelGGL(prep_weights_k, dim3(216), dim3(256), 0, stream, W0, W1, W2, W3, wt);
    hipLaunchKernelGGL(mlp_fused_k, dim3(NBLK), dim3(1024), 0, stream,
                       x, wt, bb0, bb1, bb2, bb3, out);
}

// Round 5
// 271.246 us; speedup vs baseline: 1.2515x; 1.1295x over previous
//
#include <hip/hip_runtime.h>

#define NN 200000      // nodes; D=128 features, 40 classes (padded to 48 in wt)
#define NW 16          // waves per block (W3 evicted from LDS to fit 16 waves)
#define NBLK 256       // persistent blocks (1 per CU; LDS pins 1 block/CU)
#define NT 12500       // tiles of 16 rows: 12500*16 = NN exactly
#define WSTRIDE (NBLK * NW)   // 4096 global waves

typedef __attribute__((ext_vector_type(8))) short bf16x8;
typedef __attribute__((ext_vector_type(4))) float f32x4;
typedef __attribute__((ext_vector_type(4))) unsigned int u32x4;

// round-to-nearest-even fp32 -> bf16 bits (prep kernel only)
static __device__ __forceinline__ short f2bf(float f) {
    unsigned u = __builtin_bit_cast(unsigned, f);
    u += 0x7fffu + ((u >> 16) & 1u);
    return (short)(u >> 16);
}

// pack 2 floats -> 2 bf16 in one u32 (round-half-up)
static __device__ __forceinline__ unsigned pk2(float a, float b) {
    unsigned ua = __builtin_bit_cast(unsigned, a) + 0x8000u;
    unsigned ub = __builtin_bit_cast(unsigned, b) + 0x8000u;
    return __builtin_amdgcn_perm(ub, ua, 0x07060302u);
}

// XOR-swizzled LDS offset for element (r, k) of a [*,128] bf16 table.
// 16B chunks xored with (r&15) -> conflict-free ds_read_b128 fragments.
static __device__ __forceinline__ int swz(int r, int k) {
    return (r << 7) + (((k >> 3) ^ (r & 15)) << 3) + (k & 7);
}

// Pre-transpose + bf16-convert weights into workspace (elements):
// [0) Wt0[n][k]=W0[k][n] 128x128 | [16384) Wt1 | [32768) Wt2 | [49152) Wt3 48x128 (n>=40 zero)
__global__ void prep_weights_k(const float* __restrict__ W0, const float* __restrict__ W1,
                               const float* __restrict__ W2, const float* __restrict__ W3,
                               short* __restrict__ wt) {
    int e = blockIdx.x * 256 + threadIdx.x;   // 216 blocks * 256 = 55296
    if (e < 49152) {
        int l = e >> 14;
        int i = e & 16383;
        int n = i >> 7, k = i & 127;
        const float* W = (l == 0) ? W0 : ((l == 1) ? W1 : W2);
        wt[e] = f2bf(W[(k << 7) + n]);
    } else if (e < 55296) {
        int i = e - 49152;
        int n = i >> 7, k = i & 127;
        wt[e] = (n < 40) ? f2bf(W3[k * 40 + n]) : (short)0;
    }
}

// Persistent fused 4-layer MLP + log_softmax.
// ENGINEERED TO FIT THE 64-VGPR BUDGET the allocator imposes on 1024-thread
// blocks (rounds 1/3/4: both waves-per-eu knobs ignored; demand >64 spilled
// ~120-190MB/side to scratch). Register diet:
//  - volatile bias loads (8/epilogue, L1-hit) -> not LICM-hoisted (27 regs freed)
//  - volatile W3 fragment loads (12/tile, L2-hit) -> not hoisted (48 regs freed)
//  - no cross-iteration x prefetch: raw[8] (32 regs) dies before first MFMA;
//    4 waves/EU of TLP covers the per-tile cold-load latency instead.
// Peak live set ~56 regs -> no spill at 64.
// LDS total = 98304 + 65536 = 163840 B == gfx950 max -> 1 block/CU, 16 waves (4/SIMD).
__global__ __launch_bounds__(1024) __attribute__((amdgpu_waves_per_eu(4, 4)))
void mlp_fused_k(const float* __restrict__ x, const short* __restrict__ wt,
                 const float* __restrict__ b0, const float* __restrict__ b1,
                 const float* __restrict__ b2, const float* __restrict__ b3,
                 float* __restrict__ out) {
    __shared__ __align__(16) short sW[49152];       // layers 0-2, swizzled
    __shared__ __align__(16) short sA[NW][2048];    // per-wave activation slices

    const int tid  = (int)threadIdx.x;
    const int lane = tid & 63;
    const int wv   = tid >> 6;       // wave 0..15
    const int m    = lane & 15;      // row (A) / col (B,C) within 16-tile
    const int quad = lane >> 4;      // 0..3
    short* sAw = &sA[wv][0];

    // ---- stage layers 0-2 global->LDS (swizzled), 6144 16B chunks = 6*1024 ----
    {
        const u32x4* src = (const u32x4*)wt;
        #pragma unroll
        for (int i = 0; i < 6; ++i) {
            int q = tid + i * 1024;            // exactly 6144 total, no tail
            int R = q >> 4, c = q & 15;
            *(u32x4*)&sW[(R << 7) + ((c ^ (R & 15)) << 3)] = src[q];
        }
    }
    __syncthreads();   // the ONLY barrier

    // layer-3 bias: only 3 regs, fine to hoist
    const bool val2 = (m < 8);
    const float b3v0 = b3[m], b3v1 = b3[16 + m], b3v2 = val2 ? b3[32 + m] : 0.f;

    f32x4 acc[8];
    auto zacc = [&]() {
        #pragma unroll
        for (int ct = 0; ct < 8; ++ct)
            #pragma unroll
            for (int r = 0; r < 4; ++r) acc[ct][r] = 0.f;
    };

    // bias + SiLU + bf16 -> sAw. Bias loaded VOLATILE inside (batched 8 loads,
    // L1-hit, one latency) so it is re-read per tile, never hoisted to regs.
    auto epilogue = [&](const float* bp) {
        const volatile float* vbp = bp;
        float bb[8];
        #pragma unroll
        for (int ct = 0; ct < 8; ++ct) bb[ct] = vbp[(ct << 4) + m];
        #pragma unroll
        for (int ct = 0; ct < 8; ++ct)
            #pragma unroll
            for (int r = 0; r < 4; ++r) {
                float v = acc[ct][r] + bb[ct];
                float h = v * __builtin_amdgcn_rcpf(1.f + __expf(-v));
                int rl = (quad << 2) + r;                // C/D: row = quad*4+reg
                unsigned u = __builtin_bit_cast(unsigned, h) + 0x8000u;
                sAw[swz(rl, (ct << 4) + m)] = (short)(u >> 16);
            }
    };

    // dense layer: A from wave-private slice, B from resident sW
    auto dense = [&](int lbase) {
        zacc();
        #pragma unroll
        for (int ks = 0; ks < 4; ++ks) {
            int kk = (ks << 5) + (quad << 3);
            bf16x8 a0 = *(const bf16x8*)&sAw[swz(m, kk)];
            #pragma unroll
            for (int ct = 0; ct < 8; ++ct) {
                bf16x8 b = *(const bf16x8*)&sW[lbase + swz((ct << 4) + m, kk)];
                acc[ct] = __builtin_amdgcn_mfma_f32_16x16x32_bf16(a0, b, acc[ct], 0, 0, 0);
            }
        }
    };

    // W3 fragments (12/tile) loaded VOLATILE from global: L2-resident 12KB
    // table; volatile prevents LICM from parking 48 regs of fragments.
    const volatile u32x4* w3v = (const volatile u32x4*)(wt + 49152);

    // ---- persistent tile loop (no cross-iter prefetch: keeps regs <= 64) ----
    for (int t = (int)blockIdx.x * NW + wv; t < NT; t += WSTRIDE) {
        // load + pack x for this tile; raw dies before first MFMA
        u32x4 xp[4];
        {
            f32x4 raw[8];
            const f32x4* p = (const f32x4*)(x + ((long)(t * 16 + m) << 7)) + quad * 2;
            #pragma unroll
            for (int ks = 0; ks < 4; ++ks) {
                raw[ks * 2] = p[ks * 8];
                raw[ks * 2 + 1] = p[ks * 8 + 1];
            }
            #pragma unroll
            for (int ks = 0; ks < 4; ++ks) {
                f32x4 va = raw[ks * 2], vb = raw[ks * 2 + 1];
                u32x4 ua;
                ua[0] = pk2(va[0], va[1]); ua[1] = pk2(va[2], va[3]);
                ua[2] = pk2(vb[0], vb[1]); ua[3] = pk2(vb[2], vb[3]);
                xp[ks] = ua;
            }
        }

        // layer 0: A from packed regs
        zacc();
        #pragma unroll
        for (int ks = 0; ks < 4; ++ks) {
            bf16x8 a0 = __builtin_bit_cast(bf16x8, xp[ks]);
            int kk = (ks << 5) + (quad << 3);
            #pragma unroll
            for (int ct = 0; ct < 8; ++ct) {
                bf16x8 b = *(const bf16x8*)&sW[swz((ct << 4) + m, kk)];
                acc[ct] = __builtin_amdgcn_mfma_f32_16x16x32_bf16(a0, b, acc[ct], 0, 0, 0);
            }
        }
        epilogue(b0);
        dense(16384);
        epilogue(b1);
        dense(32768);
        epilogue(b2);

        // layer 3 (48 padded cols, B volatile from global wt)
        f32x4 c3[3];
        #pragma unroll
        for (int ct = 0; ct < 3; ++ct)
            #pragma unroll
            for (int r = 0; r < 4; ++r) c3[ct][r] = 0.f;
        #pragma unroll
        for (int ks = 0; ks < 4; ++ks) {
            int kk = (ks << 5) + (quad << 3);
            bf16x8 a0 = *(const bf16x8*)&sAw[swz(m, kk)];
            #pragma unroll
            for (int ct = 0; ct < 3; ++ct) {
                u32x4 uw = w3v[(((ct << 4) + m) << 4) + (ks << 2) + quad];
                bf16x8 b = __builtin_bit_cast(bf16x8, uw);
                c3[ct] = __builtin_amdgcn_mfma_f32_16x16x32_bf16(a0, b, c3[ct], 0, 0, 0);
            }
        }
        #pragma unroll
        for (int r = 0; r < 4; ++r) {
            float v0 = c3[0][r] + b3v0;
            float v1 = c3[1][r] + b3v1;
            float v2 = c3[2][r] + b3v2;
            float mx = fmaxf(v0, v1);
            mx = val2 ? fmaxf(mx, v2) : mx;
            #pragma unroll
            for (int s = 1; s < 16; s <<= 1)
                mx = fmaxf(mx, __shfl_xor(mx, s, 64));
            float sm = __expf(v0 - mx) + __expf(v1 - mx) + (val2 ? __expf(v2 - mx) : 0.f);
            #pragma unroll
            for (int s = 1; s < 16; s <<= 1)
                sm += __shfl_xor(sm, s, 64);
            float L = mx + __logf(sm);
            int grow = t * 16 + (quad << 2) + r;   // C/D: row = quad*4+reg
            float* orow = out + (long)grow * 40;
            orow[m]      = v0 - L;
            orow[16 + m] = v1 - L;
            if (val2) orow[32 + m] = v2 - L;
        }
    }
}

extern "C" void kernel_launch(void* const* d_in, const int* in_sizes, int n_in,
                              void* d_out, int out_size, void* d_ws, size_t ws_size,
                              hipStream_t stream) {
    const float* x   = (const float*)d_in[0];
    // d_in[1] = edge_index (unused: ChebConv K=1 ignores the Laplacian)
    const float* W0  = (const float*)d_in[2];
    const float* bb0 = (const float*)d_in[3];
    const float* W1  = (const float*)d_in[4];
    const float* bb1 = (const float*)d_in[5];
    const float* W2  = (const float*)d_in[6];
    const float* bb2 = (const float*)d_in[7];
    const float* W3  = (const float*)d_in[8];
    const float* bb3 = (const float*)d_in[9];
    short* wt  = (short*)d_ws;         // 110592 B of bf16 transposed weights
    float* out = (float*)d_out;

    hipLaunchKernelGGL(prep_weights_k, dim3(216), dim3(256), 0, stream, W0, W1, W2, W3, wt);
    hipLaunchKernelGGL(mlp_fused_k, dim3(NBLK), dim3(1024), 0, stream,
                       x, wt, bb0, bb1, bb2, bb3, out);
}

// Round 6
// 216.621 us; speedup vs baseline: 1.5671x; 1.2522x over previous
//
#include <hip/hip_runtime.h>

#define NN 200000      // nodes; D=128 features, 40 classes (padded to 48 in wt)
#define NW 12          // waves per block (768 threads -> allocator grants ~84 VGPR)
#define NBLK 256       // persistent blocks (1 per CU; LDS pins 1 block/CU)
#define NT 12500       // tiles of 16 rows: 12500*16 = NN exactly
#define WSTRIDE (NBLK * NW)   // 3072 global waves

typedef __attribute__((ext_vector_type(8))) short bf16x8;
typedef __attribute__((ext_vector_type(4))) float f32x4;
typedef __attribute__((ext_vector_type(4))) unsigned int u32x4;

// round-to-nearest-even fp32 -> bf16 bits (prep kernel only)
static __device__ __forceinline__ short f2bf(float f) {
    unsigned u = __builtin_bit_cast(unsigned, f);
    u += 0x7fffu + ((u >> 16) & 1u);
    return (short)(u >> 16);
}

// pack 2 floats -> 2 bf16 in one u32 (round-half-up)
static __device__ __forceinline__ unsigned pk2(float a, float b) {
    unsigned ua = __builtin_bit_cast(unsigned, a) + 0x8000u;
    unsigned ub = __builtin_bit_cast(unsigned, b) + 0x8000u;
    return __builtin_amdgcn_perm(ub, ua, 0x07060302u);
}

// XOR-swizzled LDS offset for element (r, k) of a [*,128] bf16 table.
// 16B chunks xored with (r&15) -> conflict-free ds_read_b128 fragments.
static __device__ __forceinline__ int swz(int r, int k) {
    return (r << 7) + (((k >> 3) ^ (r & 15)) << 3) + (k & 7);
}

// Pre-transpose + bf16-convert weights into workspace (elements):
// [0) Wt0[n][k]=W0[k][n] 128x128 | [16384) Wt1 | [32768) Wt2 | [49152) Wt3 48x128 (n>=40 zero)
__global__ void prep_weights_k(const float* __restrict__ W0, const float* __restrict__ W1,
                               const float* __restrict__ W2, const float* __restrict__ W3,
                               short* __restrict__ wt) {
    int e = blockIdx.x * 256 + threadIdx.x;   // 216 blocks * 256 = 55296
    if (e < 49152) {
        int l = e >> 14;
        int i = e & 16383;
        int n = i >> 7, k = i & 127;
        const float* W = (l == 0) ? W0 : ((l == 1) ? W1 : W2);
        wt[e] = f2bf(W[(k << 7) + n]);
    } else if (e < 55296) {
        int i = e - 49152;
        int n = i >> 7, k = i & 127;
        wt[e] = (n < 40) ? f2bf(W3[k * 40 + n]) : (short)0;
    }
}

// Persistent fused 4-layer MLP + log_softmax. Round-0 geometry (768 thr,
// 12 waves, ALL weights in LDS) + proven fixes:
//  - round-4 prefetch: loop-carried raw[8], packed at loop top; next-tile
//    loads issued where acc[8] is dead -> no xc/xn double-buffer, peak live
//    set ~65 regs -> fits the 84-reg grant WITHOUT spill (round-0 had ~10MB).
//  - biases staged in LDS (1.5KB spare): epilogue reads ds_read, no L2
//    latency on the epilogue path, no 24-reg hoist requirement.
//  - s_setprio(1) around MFMA clusters (independent-wave regime: +4-7% attn).
// LDS = 110592 (sW) + 49152 (sA) + 1536 (sB) = 161280 <= 163840 -> 1 block/CU.
__global__ __launch_bounds__(768) __attribute__((amdgpu_waves_per_eu(3, 3)))
void mlp_fused_k(const float* __restrict__ x, const short* __restrict__ wt,
                 const float* __restrict__ b0, const float* __restrict__ b1,
                 const float* __restrict__ b2, const float* __restrict__ b3,
                 float* __restrict__ out) {
    __shared__ __align__(16) short sW[55296];       // all 4 layers, swizzled
    __shared__ __align__(16) short sA[NW][2048];    // per-wave activation slices
    __shared__ __align__(16) float sB[384];         // b0|b1|b2

    const int tid  = (int)threadIdx.x;
    const int lane = tid & 63;
    const int wv   = tid >> 6;       // wave 0..11
    const int m    = lane & 15;      // row (A) / col (B,C) within 16-tile
    const int quad = lane >> 4;      // 0..3
    short* sAw = &sA[wv][0];

    // ---- stage ALL weights global->LDS (swizzled), 6912 16B chunks = 9*768 ----
    {
        const u32x4* src = (const u32x4*)wt;
        #pragma unroll
        for (int i = 0; i < 9; ++i) {
            int q = tid + i * 768;             // exactly 6912 total, no tail
            int R = q >> 4, c = q & 15;
            *(u32x4*)&sW[(R << 7) + ((c ^ (R & 15)) << 3)] = src[q];
        }
        if (tid < 384)
            sB[tid] = (tid < 128) ? b0[tid] : (tid < 256) ? b1[tid - 128] : b2[tid - 256];
    }
    __syncthreads();   // the ONLY barrier

    // layer-3 bias: only 3 regs, fine to hoist
    const bool val2 = (m < 8);
    const float b3v0 = b3[m], b3v1 = b3[16 + m], b3v2 = val2 ? b3[32 + m] : 0.f;

    f32x4 acc[8];
    auto zacc = [&]() {
        #pragma unroll
        for (int ct = 0; ct < 8; ++ct)
            #pragma unroll
            for (int r = 0; r < 4; ++r) acc[ct][r] = 0.f;
    };

    // bias (from LDS) + SiLU + bf16 -> sAw (wave-private 16 rows)
    auto epilogue = [&](int lyr) {
        float bb[8];
        #pragma unroll
        for (int ct = 0; ct < 8; ++ct) bb[ct] = sB[(lyr << 7) + (ct << 4) + m];
        #pragma unroll
        for (int ct = 0; ct < 8; ++ct)
            #pragma unroll
            for (int r = 0; r < 4; ++r) {
                float v = acc[ct][r] + bb[ct];
                float h = v * __builtin_amdgcn_rcpf(1.f + __expf(-v));
                int rl = (quad << 2) + r;                // C/D: row = quad*4+reg
                unsigned u = __builtin_bit_cast(unsigned, h) + 0x8000u;
                sAw[swz(rl, (ct << 4) + m)] = (short)(u >> 16);
            }
    };

    // dense layer: A from wave-private slice, B from resident sW
    auto dense = [&](int lbase) {
        zacc();
        __builtin_amdgcn_s_setprio(1);
        #pragma unroll
        for (int ks = 0; ks < 4; ++ks) {
            int kk = (ks << 5) + (quad << 3);
            bf16x8 a0 = *(const bf16x8*)&sAw[swz(m, kk)];
            #pragma unroll
            for (int ct = 0; ct < 8; ++ct) {
                bf16x8 b = *(const bf16x8*)&sW[lbase + swz((ct << 4) + m, kk)];
                acc[ct] = __builtin_amdgcn_mfma_f32_16x16x32_bf16(a0, b, acc[ct], 0, 0, 0);
            }
        }
        __builtin_amdgcn_s_setprio(0);
    };

    // ---- persistent tile loop; x loads one tile deep, issued where acc is dead ----
    int t = (int)blockIdx.x * NW + wv;       // first tile for this wave (< WSTRIDE <= NT)
    f32x4 raw[8];                            // in-flight x (loop-carried)
    {
        const f32x4* p = (const f32x4*)(x + ((long)(t * 16 + m) << 7)) + quad * 2;
        #pragma unroll
        for (int ks = 0; ks < 4; ++ks) { raw[ks * 2] = p[ks * 8]; raw[ks * 2 + 1] = p[ks * 8 + 1]; }
    }

    while (true) {
        // pack x for CURRENT tile (loads issued last iteration / prologue)
        u32x4 xp[4];
        #pragma unroll
        for (int ks = 0; ks < 4; ++ks) {
            f32x4 va = raw[ks * 2], vb = raw[ks * 2 + 1];
            u32x4 ua;
            ua[0] = pk2(va[0], va[1]); ua[1] = pk2(va[2], va[3]);
            ua[2] = pk2(vb[0], vb[1]); ua[3] = pk2(vb[2], vb[3]);
            xp[ks] = ua;
        }

        // layer 0: A from packed regs
        zacc();
        __builtin_amdgcn_s_setprio(1);
        #pragma unroll
        for (int ks = 0; ks < 4; ++ks) {
            bf16x8 a0 = __builtin_bit_cast(bf16x8, xp[ks]);
            int kk = (ks << 5) + (quad << 3);
            #pragma unroll
            for (int ct = 0; ct < 8; ++ct) {
                bf16x8 b = *(const bf16x8*)&sW[swz((ct << 4) + m, kk)];
                acc[ct] = __builtin_amdgcn_mfma_f32_16x16x32_bf16(a0, b, acc[ct], 0, 0, 0);
            }
        }
        __builtin_amdgcn_s_setprio(0);
        epilogue(0);
        dense(16384);
        epilogue(1);
        dense(32768);
        epilogue(2);
        // acc dead from here to loop end -> raw[] reuses its register slots

        int tn = t + WSTRIDE;
        bool has = tn < NT;                   // wave-uniform
        if (has) {
            const f32x4* p = (const f32x4*)(x + ((long)(tn * 16 + m) << 7)) + quad * 2;
            #pragma unroll
            for (int ks = 0; ks < 4; ++ks) { raw[ks * 2] = p[ks * 8]; raw[ks * 2 + 1] = p[ks * 8 + 1]; }
        }

        // layer 3 (48 padded cols), B from resident sW
        f32x4 c3[3];
        #pragma unroll
        for (int ct = 0; ct < 3; ++ct)
            #pragma unroll
            for (int r = 0; r < 4; ++r) c3[ct][r] = 0.f;
        __builtin_amdgcn_s_setprio(1);
        #pragma unroll
        for (int ks = 0; ks < 4; ++ks) {
            int kk = (ks << 5) + (quad << 3);
            bf16x8 a0 = *(const bf16x8*)&sAw[swz(m, kk)];
            #pragma unroll
            for (int ct = 0; ct < 3; ++ct) {
                bf16x8 b = *(const bf16x8*)&sW[49152 + swz((ct << 4) + m, kk)];
                c3[ct] = __builtin_amdgcn_mfma_f32_16x16x32_bf16(a0, b, c3[ct], 0, 0, 0);
            }
        }
        __builtin_amdgcn_s_setprio(0);
        #pragma unroll
        for (int r = 0; r < 4; ++r) {
            float v0 = c3[0][r] + b3v0;
            float v1 = c3[1][r] + b3v1;
            float v2 = c3[2][r] + b3v2;
            float mx = fmaxf(v0, v1);
            mx = val2 ? fmaxf(mx, v2) : mx;
            #pragma unroll
            for (int s = 1; s < 16; s <<= 1)
                mx = fmaxf(mx, __shfl_xor(mx, s, 64));
            float sm = __expf(v0 - mx) + __expf(v1 - mx) + (val2 ? __expf(v2 - mx) : 0.f);
            #pragma unroll
            for (int s = 1; s < 16; s <<= 1)
                sm += __shfl_xor(sm, s, 64);
            float L = mx + __logf(sm);
            int grow = t * 16 + (quad << 2) + r;   // C/D: row = quad*4+reg
            float* orow = out + (long)grow * 40;
            orow[m]      = v0 - L;
            orow[16 + m] = v1 - L;
            if (val2) orow[32 + m] = v2 - L;
        }

        if (!has) break;
        t = tn;
    }
}

extern "C" void kernel_launch(void* const* d_in, const int* in_sizes, int n_in,
                              void* d_out, int out_size, void* d_ws, size_t ws_size,
                              hipStream_t stream) {
    const float* x   = (const float*)d_in[0];
    // d_in[1] = edge_index (unused: ChebConv K=1 ignores the Laplacian)
    const float* W0  = (const float*)d_in[2];
    const float* bb0 = (const float*)d_in[3];
    const float* W1  = (const float*)d_in[4];
    const float* bb1 = (const float*)d_in[5];
    const float* W2  = (const float*)d_in[6];
    const float* bb2 = (const float*)d_in[7];
    const float* W3  = (const float*)d_in[8];
    const float* bb3 = (const float*)d_in[9];
    short* wt  = (short*)d_ws;         // 110592 B of bf16 transposed weights
    float* out = (float*)d_out;

    hipLaunchKernelGGL(prep_weights_k, dim3(216), dim3(256), 0, stream, W0, W1, W2, W3, wt);
    hipLaunchKernelGGL(mlp_fused_k, dim3(NBLK), dim3(768), 0, stream,
                       x, wt, bb0, bb1, bb2, bb3, out);
}